// Round 12
// baseline (584.987 us; speedup 1.0000x reference)
//
#include <hip/hip_runtime.h>
#include <hip/hip_bf16.h>

typedef __attribute__((ext_vector_type(4))) float f32x4;
typedef __attribute__((ext_vector_type(8))) short s16x8;
typedef __attribute__((ext_vector_type(4))) unsigned short u16x4;

// ---- LDS layout (byte offsets), total 163840 B (160 KiB, 1 block/CU) ----
#define L_XW   0        // bf16 [64][256] swzb rows 512B (dead after LN1 -> H0)
#define L_SLAB 32768    // per head h at 32768+h*12288:
                        //   QK [64 tokens][128B]: q-packed bytes 0..63 | k-packed 64..127
                        //   P~ [64][128B] overwrites QK after B_p (all S k-reads done)
                        //   O  packed into P rows bytes 0..63 after PV reads
                        //   VT [32 d][128B] at +8192 (j-permuted)
#define L_NQ   131072   // f32 [8][64]: log2e*lsc/|q_i|  (dead after softmax -> Y)
#define L_NK   133120   // f32 [8][64]: 1/|k_j|          (dead after softmax -> Y)
#define L_Y    131072   // bf16 [64][512B] swzb (top 32KB; disjoint from slabs)
#define L_H0   0        // H chunks over XW + slabs (dead after B5)
#define L_H1   32768
#define L_H2   65536
#define L_H3   98304
#define L_MB   0        // fc2 out (over H0, after fc2-read barrier)
#define SMEM_BYTES 163840

// ---- workspace layout (byte offsets) ----
#define WSO_BIAS   0          // f32 [8][64][16][4] (h,i,c16,nt): log2e*(bias - scale_h - 16)
#define WSO_QKVW   131072     // bf16 [48][32][16][8]       393216 B
#define WSO_PROJW  524288     // bf16 [16][32][16][8]  (K d-permuted per 32-group)
#define WSO_FC1W   655360     // bf16 [64][32][16][8]       524288 B
#define WSO_FC2W   1179648    // bf16 [16][128][16][8] (K d-permuted per 32-group)
#define WSO_SIN    1703936ULL // bf16 [2][65536][256]       67108864 B
#define WSO_SOUT   68812800ULL// bf16 [2][65536][256]       67108864 B

#define LOG2E 1.4426950408f

__device__ __forceinline__ unsigned short f2bf(float f) {
  __hip_bfloat16 h = __float2bfloat16(f);
  return __builtin_bit_cast(unsigned short, h);
}
__device__ __forceinline__ float bf2f(unsigned short b) {
  union { unsigned u; float f; } v; v.u = ((unsigned)b) << 16;
  return v.f;
}
__device__ __forceinline__ int swzb(int row, int byteoff) {  // 128B+ rows, 8-way spread
  return byteoff ^ ((row & 7) << 4);
}

// ---------------- merged prep: weight pack + bias MLP + input transpose ----------------
__global__ __launch_bounds__(256)
void prep_kernel(const float* __restrict__ qkv_w,
                 const float* __restrict__ proj_w,
                 const float* __restrict__ fc1_w,
                 const float* __restrict__ fc2_w,
                 const float* __restrict__ cpb_w1,
                 const float* __restrict__ cpb_b1,
                 const float* __restrict__ cpb_w2,
                 const float* __restrict__ x,
                 const float* __restrict__ ls,
                 unsigned char* __restrict__ wsb) {
  __shared__ float tile[64][66];
  const int bid = blockIdx.x;
  const int tid = threadIdx.x;

  if (bid < 3072) {
    // ---- weight pack to MFMA fragment layout (proj/fc2: K d-perm per 32-group) ----
    int e = bid * 256 + tid;
    const float* src; unsigned short* dst; int K, N; int eo; bool perm;
    if (e < 196608)       { eo = e;          src = qkv_w;  dst = (unsigned short*)(wsb + WSO_QKVW);  K = 256;  N = 768;  perm = false; }
    else if (e < 262144)  { eo = e - 196608; src = proj_w; dst = (unsigned short*)(wsb + WSO_PROJW); K = 256;  N = 256;  perm = true; }
    else if (e < 524288)  { eo = e - 262144; src = fc1_w;  dst = (unsigned short*)(wsb + WSO_FC1W);  K = 256;  N = 1024; perm = false; }
    else                  { eo = e - 524288; src = fc2_w;  dst = (unsigned short*)(wsb + WSO_FC2W);  K = 1024; N = 256;  perm = true; }
    int j = eo & 7, c = (eo >> 3) & 15, rest = eo >> 7;
    int Kg = K >> 3;
    int kg = rest % Kg, nt = rest / Kg;
    int s = kg * 8 + j;
    if (perm) s = (s & ~31) | ((s & 1) << 4) | ((s & 31) >> 1);   // slot -> original d
    dst[eo] = f2bf(src[s * N + nt * 16 + c]);
  } else if (bid == 3072) {
    // ---- relative-position-bias via CPB MLP; log2e*(bias - scale - 16) baked ----
    float (*bt)[8] = (float(*)[8])&tile[0][0];
    for (int t = tid; t < 225; t += 256) {
      int a = t / 15, b = t % 15;
      float r0 = (float)(a - 7) * (8.0f / 7.0f);
      float r1 = (float)(b - 7) * (8.0f / 7.0f);
      float f0 = (r0 >= 0.f ? 1.f : -1.f) * log2f(fabsf(r0) + 1.f) * (1.f / 3.f);
      float f1 = (r1 >= 0.f ? 1.f : -1.f) * log2f(fabsf(r1) + 1.f) * (1.f / 3.f);
      float acc[8] = {0.f,0.f,0.f,0.f,0.f,0.f,0.f,0.f};
      for (int k = 0; k < 512; ++k) {
        float hv = f0 * cpb_w1[k] + f1 * cpb_w1[512 + k] + cpb_b1[k];
        hv = fmaxf(hv, 0.f);
        #pragma unroll
        for (int h = 0; h < 8; ++h) acc[h] += hv * cpb_w2[k * 8 + h];
      }
      #pragma unroll
      for (int h = 0; h < 8; ++h) bt[t][h] = acc[h];
    }
    __syncthreads();
    float* biasp = (float*)(wsb + WSO_BIAS);
    for (int e = tid; e < 32768; e += 256) {
      int nn = e & 3, cc = (e >> 2) & 15, i = (e >> 6) & 63, h = e >> 12;
      int j = nn * 16 + cc;
      int dr = (i >> 3) - (j >> 3) + 7, dc = (i & 7) - (j & 7) + 7;
      float v = bt[dr * 15 + dc][h];
      float scale = __expf(fminf(ls[h], 4.6051702f));
      biasp[e] = LOG2E * (16.f / (1.f + expf(-v)) - (scale + 16.f));  // logit bound <= 0 in log2 domain
    }
  } else {
    // ---- x[b][c][p] f32 -> sin[b][p][c] bf16 (tiled transpose) ----
    int b2 = bid - 3073;
    int pb = b2 & 1023;
    int cg = (b2 >> 10) & 3;
    int b  = b2 >> 12;
    int p0 = pb * 64, c0 = cg * 64;
    unsigned short* sg = (unsigned short*)(wsb + WSO_SIN);

    int pi = tid & 63, cq = tid >> 6;
    for (int r = 0; r < 16; ++r) {
      int c = cq * 16 + r;
      tile[pi][c] = x[((size_t)(b * 256 + c0 + c)) * 65536 + p0 + pi];
    }
    __syncthreads();
    int po = tid >> 2, co = tid & 3;
    s16x8 pk0, pk1;
    #pragma unroll
    for (int j = 0; j < 8; ++j) {
      pk0[j] = (short)f2bf(tile[po][co * 16 + j]);
      pk1[j] = (short)f2bf(tile[po][co * 16 + 8 + j]);
    }
    unsigned short* dp = sg + ((size_t)b * 65536 + p0 + po) * 256 + c0 + co * 16;
    *(s16x8*)(dp) = pk0;
    *(s16x8*)(dp + 8) = pk1;
  }
}

// ---------------- pass B: sout[b][p][c] bf16 -> out[b][c][p] f32 (tiled transpose) ----------------
__global__ __launch_bounds__(256)
void transpose_out_kernel(const unsigned char* __restrict__ wsb, float* __restrict__ out) {
  __shared__ float tile[64][65];
  int pb = blockIdx.x & 1023;
  int cg = (blockIdx.x >> 10) & 3;
  int b  = blockIdx.x >> 12;
  int p0 = pb * 64, c0 = cg * 64;
  int tid = threadIdx.x;
  const unsigned short* sg = (const unsigned short*)(wsb + WSO_SOUT);

  int pi = tid >> 2, cq = tid & 3;
  const unsigned short* rp = sg + ((size_t)b * 65536 + p0 + pi) * 256 + c0 + cq * 16;
  s16x8 a0 = *(const s16x8*)(rp);
  s16x8 a1 = *(const s16x8*)(rp + 8);
  #pragma unroll
  for (int j = 0; j < 8; ++j) {
    tile[pi][cq * 16 + j]     = bf2f((unsigned short)a0[j]);
    tile[pi][cq * 16 + 8 + j] = bf2f((unsigned short)a1[j]);
  }
  __syncthreads();
  int ci = tid >> 6, pi2 = tid & 63;
  for (int r = 0; r < 16; ++r) {
    int c = ci * 16 + r;
    out[((size_t)(b * 256 + c0 + c)) * 65536 + p0 + pi2] = tile[pi2][c];
  }
}

// ---------------- main fused per-window kernel: 1024 threads / 16 waves ----------------
// 16 waves/CU = 4 waves/SIMD (double round-11's occupancy) requires <=128 unified
// regs/wave -> per-wave accumulator footprint halved everywhere. Attention wave =
// (head h = w>>1, token-half = w&1).
__global__ __launch_bounds__(1024, 4)
void swin_block_kernel(const float* __restrict__ ls,
                       const float* __restrict__ proj_b,
                       const float* __restrict__ ln1w, const float* __restrict__ ln1b,
                       const float* __restrict__ fc1b,
                       const float* __restrict__ fc2b,
                       const float* __restrict__ ln2w, const float* __restrict__ ln2b,
                       unsigned char* __restrict__ wsb) {
  extern __shared__ char sm[];
  const int tid = threadIdx.x;
  const int w = tid >> 6;       // wave id 0..15
  const int lane = tid & 63;
  const int g = lane >> 4;
  const int c16 = lane & 15;
  const int h = w >> 1;         // head
  const int half = w & 1;       // token half (rows half*32 .. half*32+31)
  const int mt0 = half * 2;

  const int blk = blockIdx.x;
  const int bb = blk >> 10;
  const int widx = blk & 1023;
  const int wi = widx >> 5, wj = widx & 31;

  const f32x4* biasv = (const f32x4*)(wsb + WSO_BIAS);
  const unsigned short* qkvw = (const unsigned short*)(wsb + WSO_QKVW);
  const unsigned short* projw = (const unsigned short*)(wsb + WSO_PROJW);
  const unsigned short* fc1w = (const unsigned short*)(wsb + WSO_FC1W);
  const unsigned short* fc2w = (const unsigned short*)(wsb + WSO_FC2W);
  const unsigned short* sin_ = (const unsigned short*)(wsb + WSO_SIN);
  unsigned short* sout = (unsigned short*)(wsb + WSO_SOUT);

  // ---------- Phase 1: copy window from sin -> XW bf16 swz ----------
  #pragma unroll
  for (int it = 0; it < 2; ++it) {
    int u = tid + it * 1024;
    int t = u >> 5, cu = u & 31;
    int rp = (wi * 8 + (t >> 3) + 4) & 255;
    int cp = (wj * 8 + (t & 7) + 4) & 255;
    size_t pix = (size_t)bb * 65536 + rp * 256 + cp;
    s16x8 v = *(const s16x8*)(sin_ + pix * 256 + cu * 8);
    *(s16x8*)(sm + L_XW + t * 512 + swzb(t, cu * 16)) = v;
  }
  __syncthreads();   // B1

  char* const QB = sm + L_SLAB + h * 12288;

  // ---------- Phase Q: qkv GEMM, wave (h, half) computes head h rows half*32..+31 ----------
  {
    int tiles[6] = {2*h, 2*h+1, 16+2*h, 17+2*h, 32+2*h, 33+2*h};
    f32x4 acc[6][2];
    #pragma unroll
    for (int a = 0; a < 6; ++a)
      #pragma unroll
      for (int b = 0; b < 2; ++b) acc[a][b] = f32x4{0.f,0.f,0.f,0.f};
    #pragma unroll 4
    for (int k0 = 0; k0 < 256; k0 += 32) {
      s16x8 af[2];
      #pragma unroll
      for (int j = 0; j < 2; ++j) {
        int row = (mt0 + j) * 16 + c16;
        af[j] = *(const s16x8*)(sm + L_XW + row * 512 + swzb(row, (k0 + g * 8) * 2));
      }
      #pragma unroll
      for (int ct = 0; ct < 6; ++ct) {
        s16x8 bfr = *(const s16x8*)(qkvw + ((tiles[ct] * 32 + (k0 >> 3) + g) * 16 + c16) * 8);
        #pragma unroll
        for (int j = 0; j < 2; ++j)
          acc[ct][j] = __builtin_amdgcn_mfma_f32_16x16x32_bf16(af[j], bfr, acc[ct][j], 0, 0, 0);
      }
    }
    // epilogue: q,k packed-b32 (d'=2*(d&15)+(d>>4)); v packed-b32 pair (jp consecutive over j)
    #pragma unroll
    for (int j = 0; j < 2; ++j)
      #pragma unroll
      for (int r = 0; r < 4; ++r) {
        int i = (mt0 + j) * 16 + 4 * g + r;
        unsigned uq = (unsigned)f2bf(acc[0][j][r]) | ((unsigned)f2bf(acc[1][j][r]) << 16);
        unsigned uk = (unsigned)f2bf(acc[2][j][r]) | ((unsigned)f2bf(acc[3][j][r]) << 16);
        *(unsigned*)(QB + i * 128 + swzb(i, c16 * 4)) = uq;
        *(unsigned*)(QB + i * 128 + swzb(i, 64 + c16 * 4)) = uk;
      }
    #pragma unroll
    for (int dt = 0; dt < 2; ++dt)
      #pragma unroll
      for (int r = 0; r < 4; ++r) {
        int d = dt * 16 + c16;
        unsigned uv = (unsigned)f2bf(acc[4 + dt][0][r]) | ((unsigned)f2bf(acc[4 + dt][1][r]) << 16);
        *(unsigned*)(QB + 8192 + d * 128 + swzb(d, 8 * (4 * g + r) + 4 * half)) = uv;
      }
  }
  // norm pass (own rows, own-wave in-order): lanes 0..31 -> row half*32+lane
  if (lane < 32) {
    int row = half * 32 + lane;
    float lsc2 = LOG2E * __expf(fminf(ls[h], 4.6051702f));
    float sq = 0.f, sk2 = 0.f;
    #pragma unroll
    for (int cc4 = 0; cc4 < 4; ++cc4) {
      s16x8 qv = *(const s16x8*)(QB + row * 128 + swzb(row, cc4 * 16));
      s16x8 kv = *(const s16x8*)(QB + row * 128 + swzb(row, 64 + cc4 * 16));
      #pragma unroll
      for (int e = 0; e < 8; ++e) {
        float a = bf2f((unsigned short)qv[e]); sq  += a * a;
        float b = bf2f((unsigned short)kv[e]); sk2 += b * b;
      }
    }
    ((float*)(sm + L_NQ))[h * 64 + row] = lsc2 * __builtin_amdgcn_rsqf(fmaxf(sq, 1e-24f));
    ((float*)(sm + L_NK))[h * 64 + row] = __builtin_amdgcn_rsqf(fmaxf(sk2, 1e-24f));
  }
  __syncthreads();   // B_qkv: q,k,v + norms complete (cross-half dependency)

  // ---------- Phase A: S (own rows x all cols), softmax to regs, P store, PV ----------
  {
    s16x8 qf[2];
    #pragma unroll
    for (int j = 0; j < 2; ++j) {
      int row = (mt0 + j) * 16 + c16;
      qf[j] = *(const s16x8*)(QB + row * 128 + swzb(row, g * 16));
    }
    f32x4 S[2][4];
    #pragma unroll
    for (int nt = 0; nt < 4; ++nt) {
      int row = nt * 16 + c16;
      s16x8 kf = *(const s16x8*)(QB + row * 128 + swzb(row, 64 + g * 16));
      #pragma unroll
      for (int j = 0; j < 2; ++j)
        S[j][nt] = __builtin_amdgcn_mfma_f32_16x16x32_bf16(qf[j], kf, f32x4{0.f,0.f,0.f,0.f}, 0, 0, 0);
    }
    const float* nqp = (const float*)(sm + L_NQ) + h * 64;
    const float* nkp = (const float*)(sm + L_NK) + h * 64;
    float rk4[4];
    #pragma unroll
    for (int nt = 0; nt < 4; ++nt) rk4[nt] = nkp[nt * 16 + c16];

    u16x4 pkv[2][4];
    const bool edge = (wi == 31) || (wj == 31);
    if (edge) {
      int labj[4];
      #pragma unroll
      for (int nt = 0; nt < 4; ++nt) {
        int jj = nt * 16 + c16;
        int tr = jj >> 3, tc = jj & 7;
        labj[nt] = ((wi == 31) ? (tr >= 4 ? 2 : 1) : 0) * 3 + ((wj == 31) ? (tc >= 4 ? 2 : 1) : 0);
      }
      #pragma unroll
      for (int j = 0; j < 2; ++j)
        #pragma unroll
        for (int r = 0; r < 4; ++r) {
          int i = (mt0 + j) * 16 + 4 * g + r;
          float rq = nqp[i];
          f32x4 bb4 = biasv[(h * 64 + i) * 16 + c16];
          int tr = i >> 3, tc = i & 7;
          int labi = ((wi == 31) ? (tr >= 4 ? 2 : 1) : 0) * 3 + ((wj == 31) ? (tc >= 4 ? 2 : 1) : 0);
          #pragma unroll
          for (int nt = 0; nt < 4; ++nt) {
            float vx = fmaf(S[j][nt][r] * rk4[nt], rq, bb4[nt]);
            if (labi != labj[nt]) vx -= 144.2695f;
            pkv[j][r][nt] = f2bf(__builtin_amdgcn_exp2f(vx));
          }
        }
    } else {
      #pragma unroll
      for (int j = 0; j < 2; ++j)
        #pragma unroll
        for (int r = 0; r < 4; ++r) {
          int i = (mt0 + j) * 16 + 4 * g + r;
          float rq = nqp[i];
          f32x4 bb4 = biasv[(h * 64 + i) * 16 + c16];
          #pragma unroll
          for (int nt = 0; nt < 4; ++nt) {
            float vx = fmaf(S[j][nt][r] * rk4[nt], rq, bb4[nt]);
            pkv[j][r][nt] = f2bf(__builtin_amdgcn_exp2f(vx));
          }
        }
    }
    __syncthreads();   // B_p: all waves' S k-reads done; safe to overwrite QK with P~

    #pragma unroll
    for (int j = 0; j < 2; ++j)
      #pragma unroll
      for (int r = 0; r < 4; ++r) {
        int i = (mt0 + j) * 16 + 4 * g + r;
        *(u16x4*)(QB + i * 128 + swzb(i, c16 * 8)) = pkv[j][r];
      }

    // PV + rowsum-via-ones (own rows)
    s16x8 ones;
    #pragma unroll
    for (int e = 0; e < 8; ++e) ones[e] = (short)0x3F80;
    f32x4 O[2][2], RS[2];
    #pragma unroll
    for (int a = 0; a < 2; ++a) {
      O[a][0] = f32x4{0.f,0.f,0.f,0.f};
      O[a][1] = f32x4{0.f,0.f,0.f,0.f};
      RS[a]   = f32x4{0.f,0.f,0.f,0.f};
    }
    #pragma unroll
    for (int k0 = 0; k0 < 64; k0 += 32) {
      s16x8 pf[2];
      #pragma unroll
      for (int j = 0; j < 2; ++j) {
        int row = (mt0 + j) * 16 + c16;
        pf[j] = *(const s16x8*)(QB + row * 128 + swzb(row, (k0 + g * 8) * 2));
      }
      #pragma unroll
      for (int nt = 0; nt < 2; ++nt) {
        int d = nt * 16 + c16;
        s16x8 vf = *(const s16x8*)(QB + 8192 + d * 128 + swzb(d, (k0 + g * 8) * 2));
        #pragma unroll
        for (int j = 0; j < 2; ++j)
          O[j][nt] = __builtin_amdgcn_mfma_f32_16x16x32_bf16(pf[j], vf, O[j][nt], 0, 0, 0);
      }
      #pragma unroll
      for (int j = 0; j < 2; ++j)
        RS[j] = __builtin_amdgcn_mfma_f32_16x16x32_bf16(pf[j], ones, RS[j], 0, 0, 0);
    }
    // normalize + packed O store into own P rows bytes 0..63
    #pragma unroll
    for (int j = 0; j < 2; ++j)
      #pragma unroll
      for (int r = 0; r < 4; ++r) {
        float inv = __builtin_amdgcn_rcpf(fmaxf(RS[j][r], 1e-35f));
        int i = (mt0 + j) * 16 + 4 * g + r;
        unsigned u = (unsigned)f2bf(O[j][0][r] * inv) | ((unsigned)f2bf(O[j][1][r] * inv) << 16);
        *(unsigned*)(QB + i * 128 + swzb(i, c16 * 4)) = u;
      }
  }
  __syncthreads();   // B2: all heads' O complete

  // ---------- Phase P: proj; wave w -> col-tile w (of 16). Y disjoint, no extra barrier ----------
  {
    f32x4 aP[4];
    #pragma unroll
    for (int b = 0; b < 4; ++b) aP[b] = f32x4{0.f,0.f,0.f,0.f};
    #pragma unroll 2
    for (int hk = 0; hk < 8; ++hk) {
      const char* OBk = sm + L_SLAB + hk * 12288;
      s16x8 af[4];
      #pragma unroll
      for (int mt = 0; mt < 4; ++mt) {
        int row = mt * 16 + c16;
        af[mt] = *(const s16x8*)(OBk + row * 128 + swzb(row, g * 16));
      }
      s16x8 bfr = *(const s16x8*)(projw + ((w * 32 + 4*hk + g) * 16 + c16) * 8);
      #pragma unroll
      for (int mt = 0; mt < 4; ++mt)
        aP[mt] = __builtin_amdgcn_mfma_f32_16x16x32_bf16(af[mt], bfr, aP[mt], 0, 0, 0);
    }
    int col = w * 16 + c16;
    float pb = proj_b[col];
    #pragma unroll
    for (int mt = 0; mt < 4; ++mt)
      #pragma unroll
      for (int r = 0; r < 4; ++r) {
        int i = mt * 16 + 4 * g + r;
        *(unsigned short*)(sm + L_Y + i * 512 + swzb(i, col * 2)) = f2bf(aP[mt][r] + pb);
      }
  }
  __syncthreads();   // B4 (Y complete; NQ/NK dead)

  // ---------- LN1 + residual: y = LN(o)*g+b + xw, in place on Y; 16 lanes/row ----------
  {
    int t = tid >> 4, lc = tid & 15;
    float v[16];
    float s1 = 0.f;
    #pragma unroll
    for (int b2 = 0; b2 < 2; ++b2) {
      s16x8 vb = *(const s16x8*)(sm + L_Y + t * 512 + swzb(t, lc * 32 + b2 * 16));
      #pragma unroll
      for (int e = 0; e < 8; ++e) { float fv = bf2f((unsigned short)vb[e]); v[b2*8+e] = fv; s1 += fv; }
    }
    s1 += __shfl_xor(s1, 1);
    s1 += __shfl_xor(s1, 2);
    s1 += __shfl_xor(s1, 4);
    s1 += __shfl_xor(s1, 8);
    float mu = s1 * (1.f / 256.f);
    float s2 = 0.f;
    #pragma unroll
    for (int e = 0; e < 16; ++e) { float d = v[e] - mu; s2 += d * d; }
    s2 += __shfl_xor(s2, 1);
    s2 += __shfl_xor(s2, 2);
    s2 += __shfl_xor(s2, 4);
    s2 += __shfl_xor(s2, 8);
    float rs = __builtin_amdgcn_rsqf(s2 * (1.f / 256.f) + 1e-5f);
    #pragma unroll
    for (int b2 = 0; b2 < 2; ++b2) {
      s16x8 xb = *(const s16x8*)(sm + L_XW + t * 512 + swzb(t, lc * 32 + b2 * 16));
      s16x8 yb;
      #pragma unroll
      for (int e = 0; e < 8; ++e) {
        int c = lc * 16 + b2 * 8 + e;
        float yv = (v[b2*8+e] - mu) * rs * ln1w[c] + ln1b[c] + bf2f((unsigned short)xb[e]);
        yb[e] = (short)f2bf(yv);
      }
      *(s16x8*)(sm + L_Y + t * 512 + swzb(t, lc * 32 + b2 * 16)) = yb;
    }
  }
  __syncthreads();   // B5: Y final; XW/slabs dead -> H buffers

  // ---------- MLP fc1: wave w -> chunk cc=w>>2, tiles (w&3)*4..+3; barrier-free ----------
  {
    const int Hoff[4] = {L_H0, L_H1, L_H2, L_H3};
    const int cc = w >> 2;
    const int gt0 = cc * 16 + (w & 3) * 4;
    char* HB = sm + Hoff[cc];
    f32x4 acc1[4][4];
    #pragma unroll
    for (int a = 0; a < 4; ++a)
      #pragma unroll
      for (int m = 0; m < 4; ++m) acc1[a][m] = f32x4{0.f,0.f,0.f,0.f};
    for (int k0 = 0; k0 < 256; k0 += 32) {
      s16x8 af[4];
      #pragma unroll
      for (int mt = 0; mt < 4; ++mt) {
        int row = mt * 16 + c16;
        af[mt] = *(const s16x8*)(sm + L_Y + row * 512 + swzb(row, (k0 + g * 8) * 2));
      }
      #pragma unroll
      for (int ct = 0; ct < 4; ++ct) {
        s16x8 bfr = *(const s16x8*)(fc1w + (((gt0 + ct) * 32 + (k0 >> 3) + g) * 16 + c16) * 8);
        #pragma unroll
        for (int mt = 0; mt < 4; ++mt)
          acc1[ct][mt] = __builtin_amdgcn_mfma_f32_16x16x32_bf16(af[mt], bfr, acc1[ct][mt], 0, 0, 0);
      }
    }
    // sigmoid-form gelu; pack (ct even, ct odd) pairs per 32-group (perm baked in fc2w)
    float b1v[4];
    #pragma unroll
    for (int ct = 0; ct < 4; ++ct) b1v[ct] = fc1b[(gt0 + ct) * 16 + c16];
    #pragma unroll
    for (int cp2 = 0; cp2 < 2; ++cp2) {
      #pragma unroll
      for (int mt = 0; mt < 4; ++mt)
        #pragma unroll
        for (int r = 0; r < 4; ++r) {
          int i = mt * 16 + 4 * g + r;
          float u0 = acc1[cp2 * 2][mt][r] + b1v[cp2 * 2];
          float u1 = acc1[cp2 * 2 + 1][mt][r] + b1v[cp2 * 2 + 1];
          float e0 = __builtin_amdgcn_exp2f(-2.45538f * u0);
          float e1 = __builtin_amdgcn_exp2f(-2.45538f * u1);
          float g0 = u0 * __builtin_amdgcn_rcpf(1.f + e0);
          float g1 = u1 * __builtin_amdgcn_rcpf(1.f + e1);
          unsigned u = (unsigned)f2bf(g0) | ((unsigned)f2bf(g1) << 16);
          *(unsigned*)(HB + i * 512 + swzb(i, ((w & 3) * 2 + cp2) * 64 + c16 * 4)) = u;
        }
    }
  }
  __syncthreads();   // B6: all H complete

  // ---------- MLP fc2: wave w -> col-tile w; barrier-free over K=1024 ----------
  f32x4 acc2[4];
  #pragma unroll
  for (int b = 0; b < 4; ++b) acc2[b] = f32x4{0.f,0.f,0.f,0.f};
  {
    const int Hoff[4] = {L_H0, L_H1, L_H2, L_H3};
    #pragma unroll 1
    for (int cc = 0; cc < 4; ++cc) {
      const char* HB = sm + Hoff[cc];
      for (int k0 = 0; k0 < 256; k0 += 32) {
        s16x8 af[4];
        #pragma unroll
        for (int mt = 0; mt < 4; ++mt) {
          int row = mt * 16 + c16;
          af[mt] = *(const s16x8*)(HB + row * 512 + swzb(row, (k0 + g * 8) * 2));
        }
        int kg = cc * 32 + (k0 >> 3) + g;
        s16x8 bfr = *(const s16x8*)(fc2w + ((w * 128 + kg) * 16 + c16) * 8);
        #pragma unroll
        for (int mt = 0; mt < 4; ++mt)
          acc2[mt] = __builtin_amdgcn_mfma_f32_16x16x32_bf16(af[mt], bfr, acc2[mt], 0, 0, 0);
      }
    }
  }
  __syncthreads();   // B7: fc2 H reads done (MB overwrites H0)

  // ---------- fc2 epilogue -> MB ----------
  {
    int col = w * 16 + c16;
    float b2v = fc2b[col];
    #pragma unroll
    for (int mt = 0; mt < 4; ++mt)
      #pragma unroll
      for (int r = 0; r < 4; ++r) {
        int i = mt * 16 + 4 * g + r;
        *(unsigned short*)(sm + L_MB + i * 512 + swzb(i, col * 2)) = f2bf(acc2[mt][r] + b2v);
      }
  }
  __syncthreads();   // B8

  // ---------- LN2 + residual; direct bf16 store to sout (32B/lane contiguous) ----------
  {
    int t2 = tid >> 4, lc = tid & 15;
    float v[16];
    float s1 = 0.f;
    #pragma unroll
    for (int b2 = 0; b2 < 2; ++b2) {
      s16x8 vb = *(const s16x8*)(sm + L_MB + t2 * 512 + swzb(t2, lc * 32 + b2 * 16));
      #pragma unroll
      for (int e = 0; e < 8; ++e) { float fv = bf2f((unsigned short)vb[e]); v[b2*8+e] = fv; s1 += fv; }
    }
    s1 += __shfl_xor(s1, 1);
    s1 += __shfl_xor(s1, 2);
    s1 += __shfl_xor(s1, 4);
    s1 += __shfl_xor(s1, 8);
    float mu = s1 * (1.f / 256.f);
    float s2 = 0.f;
    #pragma unroll
    for (int e = 0; e < 16; ++e) { float d = v[e] - mu; s2 += d * d; }
    s2 += __shfl_xor(s2, 1);
    s2 += __shfl_xor(s2, 2);
    s2 += __shfl_xor(s2, 4);
    s2 += __shfl_xor(s2, 8);
    float rs = __builtin_amdgcn_rsqf(s2 * (1.f / 256.f) + 1e-5f);
    int rp = (wi * 8 + (t2 >> 3) + 4) & 255;
    int cp = (wj * 8 + (t2 & 7) + 4) & 255;
    size_t pix = (size_t)bb * 65536 + rp * 256 + cp;
    unsigned short* so = sout + pix * 256 + lc * 16;
    #pragma unroll
    for (int b2 = 0; b2 < 2; ++b2) {
      s16x8 yb = *(const s16x8*)(sm + L_Y + t2 * 512 + swzb(t2, lc * 32 + b2 * 16));
      s16x8 pk;
      #pragma unroll
      for (int e = 0; e < 8; ++e) {
        int c = lc * 16 + b2 * 8 + e;
        float yv = (v[b2*8+e] - mu) * rs * ln2w[c] + ln2b[c] + bf2f((unsigned short)yb[e]);
        pk[e] = (short)f2bf(yv);
      }
      *(s16x8*)(so + b2 * 8) = pk;
    }
  }
}

extern "C" void kernel_launch(void* const* d_in, const int* in_sizes, int n_in,
                              void* d_out, int out_size, void* d_ws, size_t ws_size,
                              hipStream_t stream) {
  const float* x      = (const float*)d_in[0];
  const float* qkv_w  = (const float*)d_in[1];
  const float* ls     = (const float*)d_in[2];
  const float* proj_w = (const float*)d_in[3];
  const float* proj_b = (const float*)d_in[4];
  const float* ln1w   = (const float*)d_in[5];
  const float* ln1b   = (const float*)d_in[6];
  const float* fc1_w  = (const float*)d_in[7];
  const float* fc1b   = (const float*)d_in[8];
  const float* fc2_w  = (const float*)d_in[9];
  const float* fc2b   = (const float*)d_in[10];
  const float* ln2w   = (const float*)d_in[11];
  const float* ln2b   = (const float*)d_in[12];
  const float* cpb_w1 = (const float*)d_in[13];
  const float* cpb_b1 = (const float*)d_in[14];
  const float* cpb_w2 = (const float*)d_in[15];
  unsigned char* wsb = (unsigned char*)d_ws;
  float* out = (float*)d_out;

  hipFuncSetAttribute(reinterpret_cast<const void*>(swin_block_kernel),
                      hipFuncAttributeMaxDynamicSharedMemorySize, SMEM_BYTES);

  prep_kernel<<<11265, 256, 0, stream>>>(qkv_w, proj_w, fc1_w, fc2_w,
                                         cpb_w1, cpb_b1, cpb_w2, x, ls, wsb);
  swin_block_kernel<<<2048, 1024, SMEM_BYTES, stream>>>(
      ls, proj_b, ln1w, ln1b, fc1b, fc2b, ln2w, ln2b, wsb);
  transpose_out_kernel<<<8192, 256, 0, stream>>>(wsb, out);
}

// Round 13
// 467.811 us; speedup vs baseline: 1.2505x; 1.2505x over previous
//
#include <hip/hip_runtime.h>
#include <hip/hip_bf16.h>

typedef __attribute__((ext_vector_type(4))) float f32x4;
typedef __attribute__((ext_vector_type(8))) short s16x8;
typedef __attribute__((ext_vector_type(4))) unsigned short u16x4;

// ---- LDS layout (byte offsets), total 163840 B (160 KiB, 1 block/CU) ----
#define L_XW   0        // bf16 [64][256] swzb rows 512B (dead after LN1 -> H0)
#define L_SLAB 32768    // per head h at 32768+h*12288:
                        //   QK [64 tokens][128B]: q-packed bytes 0..63 | k-packed 64..127
                        //   P~ [64][128B] overwrites QK after S reads (same-wave order)
                        //   O  packed into P rows bytes 0..63 after PV reads
                        //   VT [32 d][128B] at +8192 (j-permuted)
#define L_NQ   131072   // f32 [8][64]: log2e*lsc/|q_i|  (dead after softmax -> Y)
#define L_NK   133120   // f32 [8][64]: 1/|k_j|          (dead after softmax -> Y)
#define L_Y    131072   // bf16 [64][512B] swzb (top 32KB; disjoint from slabs)
#define L_H0   0        // H chunks over XW + slabs (dead after B5)
#define L_H1   32768
#define L_H2   65536
#define L_H3   98304
#define L_MB   0        // fc2 out (over H0, after fc2-read barrier)
#define SMEM_BYTES 163840

// ---- workspace layout (byte offsets) ----
#define WSO_BIAS   0          // f32 [8][64][16][4] (h,i,c16,nt): log2e*(bias - scale_h - 16)
#define WSO_QKVW   131072     // bf16 [48][32][16][8]       393216 B
#define WSO_PROJW  524288     // bf16 [16][32][16][8]  (K d-permuted per 32-group)
#define WSO_FC1W   655360     // bf16 [64][32][16][8]       524288 B
#define WSO_FC2W   1179648    // bf16 [16][128][16][8] (K d-permuted per 32-group)
#define WSO_SIN    1703936ULL // bf16 [2][65536][256]       67108864 B
#define WSO_SOUT   68812800ULL// bf16 [2][65536][256]       67108864 B

#define LOG2E 1.4426950408f

__device__ __forceinline__ unsigned short f2bf(float f) {
  __hip_bfloat16 h = __float2bfloat16(f);
  return __builtin_bit_cast(unsigned short, h);
}
__device__ __forceinline__ float bf2f(unsigned short b) {
  union { unsigned u; float f; } v; v.u = ((unsigned)b) << 16;
  return v.f;
}
__device__ __forceinline__ int swzb(int row, int byteoff) {  // 128B+ rows, 8-way spread
  return byteoff ^ ((row & 7) << 4);
}

// ---------------- merged prep: weight pack + bias MLP + input transpose ----------------
__global__ __launch_bounds__(256)
void prep_kernel(const float* __restrict__ qkv_w,
                 const float* __restrict__ proj_w,
                 const float* __restrict__ fc1_w,
                 const float* __restrict__ fc2_w,
                 const float* __restrict__ cpb_w1,
                 const float* __restrict__ cpb_b1,
                 const float* __restrict__ cpb_w2,
                 const float* __restrict__ x,
                 const float* __restrict__ ls,
                 unsigned char* __restrict__ wsb) {
  __shared__ float tile[64][66];
  const int bid = blockIdx.x;
  const int tid = threadIdx.x;

  if (bid < 3072) {
    // ---- weight pack to MFMA fragment layout (proj/fc2: K d-perm per 32-group) ----
    int e = bid * 256 + tid;
    const float* src; unsigned short* dst; int K, N; int eo; bool perm;
    if (e < 196608)       { eo = e;          src = qkv_w;  dst = (unsigned short*)(wsb + WSO_QKVW);  K = 256;  N = 768;  perm = false; }
    else if (e < 262144)  { eo = e - 196608; src = proj_w; dst = (unsigned short*)(wsb + WSO_PROJW); K = 256;  N = 256;  perm = true; }
    else if (e < 524288)  { eo = e - 262144; src = fc1_w;  dst = (unsigned short*)(wsb + WSO_FC1W);  K = 256;  N = 1024; perm = false; }
    else                  { eo = e - 524288; src = fc2_w;  dst = (unsigned short*)(wsb + WSO_FC2W);  K = 1024; N = 256;  perm = true; }
    int j = eo & 7, c = (eo >> 3) & 15, rest = eo >> 7;
    int Kg = K >> 3;
    int kg = rest % Kg, nt = rest / Kg;
    int s = kg * 8 + j;
    if (perm) s = (s & ~31) | ((s & 1) << 4) | ((s & 31) >> 1);   // slot -> original d
    dst[eo] = f2bf(src[s * N + nt * 16 + c]);
  } else if (bid == 3072) {
    // ---- relative-position-bias via CPB MLP; log2e*(bias - scale - 16) baked ----
    float (*bt)[8] = (float(*)[8])&tile[0][0];
    for (int t = tid; t < 225; t += 256) {
      int a = t / 15, b = t % 15;
      float r0 = (float)(a - 7) * (8.0f / 7.0f);
      float r1 = (float)(b - 7) * (8.0f / 7.0f);
      float f0 = (r0 >= 0.f ? 1.f : -1.f) * log2f(fabsf(r0) + 1.f) * (1.f / 3.f);
      float f1 = (r1 >= 0.f ? 1.f : -1.f) * log2f(fabsf(r1) + 1.f) * (1.f / 3.f);
      float acc[8] = {0.f,0.f,0.f,0.f,0.f,0.f,0.f,0.f};
      for (int k = 0; k < 512; ++k) {
        float hv = f0 * cpb_w1[k] + f1 * cpb_w1[512 + k] + cpb_b1[k];
        hv = fmaxf(hv, 0.f);
        #pragma unroll
        for (int h = 0; h < 8; ++h) acc[h] += hv * cpb_w2[k * 8 + h];
      }
      #pragma unroll
      for (int h = 0; h < 8; ++h) bt[t][h] = acc[h];
    }
    __syncthreads();
    float* biasp = (float*)(wsb + WSO_BIAS);
    for (int e = tid; e < 32768; e += 256) {
      int nn = e & 3, cc = (e >> 2) & 15, i = (e >> 6) & 63, h = e >> 12;
      int j = nn * 16 + cc;
      int dr = (i >> 3) - (j >> 3) + 7, dc = (i & 7) - (j & 7) + 7;
      float v = bt[dr * 15 + dc][h];
      float scale = __expf(fminf(ls[h], 4.6051702f));
      biasp[e] = LOG2E * (16.f / (1.f + expf(-v)) - (scale + 16.f));  // logit bound <= 0 in log2 domain
    }
  } else {
    // ---- x[b][c][p] f32 -> sin[b][p][c] bf16 (tiled transpose) ----
    int b2 = bid - 3073;
    int pb = b2 & 1023;
    int cg = (b2 >> 10) & 3;
    int b  = b2 >> 12;
    int p0 = pb * 64, c0 = cg * 64;
    unsigned short* sg = (unsigned short*)(wsb + WSO_SIN);

    int pi = tid & 63, cq = tid >> 6;
    for (int r = 0; r < 16; ++r) {
      int c = cq * 16 + r;
      tile[pi][c] = x[((size_t)(b * 256 + c0 + c)) * 65536 + p0 + pi];
    }
    __syncthreads();
    int po = tid >> 2, co = tid & 3;
    s16x8 pk0, pk1;
    #pragma unroll
    for (int j = 0; j < 8; ++j) {
      pk0[j] = (short)f2bf(tile[po][co * 16 + j]);
      pk1[j] = (short)f2bf(tile[po][co * 16 + 8 + j]);
    }
    unsigned short* dp = sg + ((size_t)b * 65536 + p0 + po) * 256 + c0 + co * 16;
    *(s16x8*)(dp) = pk0;
    *(s16x8*)(dp + 8) = pk1;
  }
}

// ---------------- pass B: sout[b][p][c] bf16 -> out[b][c][p] f32 (tiled transpose) ----------------
__global__ __launch_bounds__(256)
void transpose_out_kernel(const unsigned char* __restrict__ wsb, float* __restrict__ out) {
  __shared__ float tile[64][65];
  int pb = blockIdx.x & 1023;
  int cg = (blockIdx.x >> 10) & 3;
  int b  = blockIdx.x >> 12;
  int p0 = pb * 64, c0 = cg * 64;
  int tid = threadIdx.x;
  const unsigned short* sg = (const unsigned short*)(wsb + WSO_SOUT);

  int pi = tid >> 2, cq = tid & 3;
  const unsigned short* rp = sg + ((size_t)b * 65536 + p0 + pi) * 256 + c0 + cq * 16;
  s16x8 a0 = *(const s16x8*)(rp);
  s16x8 a1 = *(const s16x8*)(rp + 8);
  #pragma unroll
  for (int j = 0; j < 8; ++j) {
    tile[pi][cq * 16 + j]     = bf2f((unsigned short)a0[j]);
    tile[pi][cq * 16 + 8 + j] = bf2f((unsigned short)a1[j]);
  }
  __syncthreads();
  int ci = tid >> 6, pi2 = tid & 63;
  for (int r = 0; r < 16; ++r) {
    int c = ci * 16 + r;
    out[((size_t)(b * 256 + c0 + c)) * 65536 + p0 + pi2] = tile[pi2][c];
  }
}

// ---------------- main fused per-window kernel: 512 threads / 8 waves, wave=head ----------------
// 2 waves/SIMD is the hard occupancy ceiling (unified VGPR file; round-12 (1024,4)
// experiment spilled at 64 arch VGPRs). LDS spent freely at 160 KiB, 1 block/CU.
__global__ __launch_bounds__(512, 2)
void swin_block_kernel(const float* __restrict__ ls,
                       const float* __restrict__ proj_b,
                       const float* __restrict__ ln1w, const float* __restrict__ ln1b,
                       const float* __restrict__ fc1b,
                       const float* __restrict__ fc2b,
                       const float* __restrict__ ln2w, const float* __restrict__ ln2b,
                       unsigned char* __restrict__ wsb) {
  extern __shared__ char sm[];
  const int tid = threadIdx.x;
  const int w = tid >> 6;       // wave id = head id in attention
  const int lane = tid & 63;
  const int g = lane >> 4;
  const int c16 = lane & 15;

  const int blk = blockIdx.x;
  const int bb = blk >> 10;
  const int widx = blk & 1023;
  const int wi = widx >> 5, wj = widx & 31;

  const f32x4* biasv = (const f32x4*)(wsb + WSO_BIAS);
  const unsigned short* qkvw = (const unsigned short*)(wsb + WSO_QKVW);
  const unsigned short* projw = (const unsigned short*)(wsb + WSO_PROJW);
  const unsigned short* fc1w = (const unsigned short*)(wsb + WSO_FC1W);
  const unsigned short* fc2w = (const unsigned short*)(wsb + WSO_FC2W);
  const unsigned short* sin_ = (const unsigned short*)(wsb + WSO_SIN);
  unsigned short* sout = (unsigned short*)(wsb + WSO_SOUT);

  // ---------- Phase 1: copy window from sin -> XW bf16 swz ----------
  #pragma unroll
  for (int it = 0; it < 4; ++it) {
    int u = tid + it * 512;
    int t = u >> 5, cu = u & 31;
    int rp = (wi * 8 + (t >> 3) + 4) & 255;
    int cp = (wj * 8 + (t & 7) + 4) & 255;
    size_t pix = (size_t)bb * 65536 + rp * 256 + cp;
    s16x8 v = *(const s16x8*)(sin_ + pix * 256 + cu * 8);
    *(s16x8*)(sm + L_XW + t * 512 + swzb(t, cu * 16)) = v;
  }
  __syncthreads();   // B1

  char* const QB = sm + L_SLAB + w * 12288;

  // ---------- Phase Q: qkv GEMM, wave w computes head w ----------
  {
    int tiles[6] = {2*w, 2*w+1, 16+2*w, 17+2*w, 32+2*w, 33+2*w};
    f32x4 acc[6][4];
    #pragma unroll
    for (int a = 0; a < 6; ++a)
      #pragma unroll
      for (int b = 0; b < 4; ++b) acc[a][b] = f32x4{0.f,0.f,0.f,0.f};
    __builtin_amdgcn_s_setprio(1);
    #pragma unroll 4
    for (int k0 = 0; k0 < 256; k0 += 32) {
      s16x8 af[4];
      #pragma unroll
      for (int mt = 0; mt < 4; ++mt) {
        int row = mt * 16 + c16;
        af[mt] = *(const s16x8*)(sm + L_XW + row * 512 + swzb(row, (k0 + g * 8) * 2));
      }
      #pragma unroll
      for (int ct = 0; ct < 6; ++ct) {
        s16x8 bfr = *(const s16x8*)(qkvw + ((tiles[ct] * 32 + (k0 >> 3) + g) * 16 + c16) * 8);
        #pragma unroll
        for (int mt = 0; mt < 4; ++mt)
          acc[ct][mt] = __builtin_amdgcn_mfma_f32_16x16x32_bf16(af[mt], bfr, acc[ct][mt], 0, 0, 0);
      }
    }
    __builtin_amdgcn_s_setprio(0);
    // epilogue: q,k packed-b32 (d' = 2*(d&15)+(d>>4)); v packed-b64 (4 mt -> 4 consecutive jp)
    #pragma unroll
    for (int mt = 0; mt < 4; ++mt)
      #pragma unroll
      for (int r = 0; r < 4; ++r) {
        int i = mt * 16 + 4 * g + r;
        unsigned uq = (unsigned)f2bf(acc[0][mt][r]) | ((unsigned)f2bf(acc[1][mt][r]) << 16);
        unsigned uk = (unsigned)f2bf(acc[2][mt][r]) | ((unsigned)f2bf(acc[3][mt][r]) << 16);
        *(unsigned*)(QB + i * 128 + swzb(i, c16 * 4)) = uq;
        *(unsigned*)(QB + i * 128 + swzb(i, 64 + c16 * 4)) = uk;
      }
    #pragma unroll
    for (int dt = 0; dt < 2; ++dt)
      #pragma unroll
      for (int r = 0; r < 4; ++r) {
        int d = dt * 16 + c16;
        u16x4 vv;
        #pragma unroll
        for (int mt = 0; mt < 4; ++mt) vv[mt] = f2bf(acc[4 + dt][mt][r]);
        *(u16x4*)(QB + 8192 + d * 128 + swzb(d, 8 * (4 * g + r))) = vv;
      }
  }
  // norm pass (wave-private; DS in-order): lane reads q-row `lane` and k-row `lane`
  {
    float lsc2 = LOG2E * __expf(fminf(ls[w], 4.6051702f));
    float sq = 0.f, sk2 = 0.f;
    #pragma unroll
    for (int cc4 = 0; cc4 < 4; ++cc4) {
      s16x8 qv = *(const s16x8*)(QB + lane * 128 + swzb(lane, cc4 * 16));
      s16x8 kv = *(const s16x8*)(QB + lane * 128 + swzb(lane, 64 + cc4 * 16));
      #pragma unroll
      for (int e = 0; e < 8; ++e) {
        float a = bf2f((unsigned short)qv[e]); sq  += a * a;
        float b = bf2f((unsigned short)kv[e]); sk2 += b * b;
      }
    }
    ((float*)(sm + L_NQ))[w * 64 + lane] = lsc2 * __builtin_amdgcn_rsqf(fmaxf(sq, 1e-24f));
    ((float*)(sm + L_NK))[w * 64 + lane] = __builtin_amdgcn_rsqf(fmaxf(sk2, 1e-24f));
  }

  // ---------- Phase A: S, bounded exp2 softmax (no reductions), PV + MFMA row-sums ----------
  {
    s16x8 qf[4];
    #pragma unroll
    for (int mt = 0; mt < 4; ++mt) {
      int row = mt * 16 + c16;
      qf[mt] = *(const s16x8*)(QB + row * 128 + swzb(row, g * 16));
    }
    f32x4 S[4][4];
    __builtin_amdgcn_s_setprio(1);
    #pragma unroll
    for (int nt = 0; nt < 4; ++nt) {
      int row = nt * 16 + c16;
      s16x8 kf = *(const s16x8*)(QB + row * 128 + swzb(row, 64 + g * 16));
      #pragma unroll
      for (int mt = 0; mt < 4; ++mt)
        S[mt][nt] = __builtin_amdgcn_mfma_f32_16x16x32_bf16(qf[mt], kf, f32x4{0.f,0.f,0.f,0.f}, 0, 0, 0);
    }
    __builtin_amdgcn_s_setprio(0);
    const float* nqp = (const float*)(sm + L_NQ) + w * 64;
    const float* nkp = (const float*)(sm + L_NK) + w * 64;
    float rk4[4];
    #pragma unroll
    for (int nt = 0; nt < 4; ++nt) rk4[nt] = nkp[nt * 16 + c16];

    const bool edge = (wi == 31) || (wj == 31);
    if (edge) {
      int labj[4];
      #pragma unroll
      for (int nt = 0; nt < 4; ++nt) {
        int jj = nt * 16 + c16;
        int tr = jj >> 3, tc = jj & 7;
        labj[nt] = ((wi == 31) ? (tr >= 4 ? 2 : 1) : 0) * 3 + ((wj == 31) ? (tc >= 4 ? 2 : 1) : 0);
      }
      #pragma unroll
      for (int mt = 0; mt < 4; ++mt)
        #pragma unroll
        for (int r = 0; r < 4; ++r) {
          int i = mt * 16 + 4 * g + r;
          float rq = nqp[i];
          f32x4 bb4 = biasv[(w * 64 + i) * 16 + c16];
          int tr = i >> 3, tc = i & 7;
          int labi = ((wi == 31) ? (tr >= 4 ? 2 : 1) : 0) * 3 + ((wj == 31) ? (tc >= 4 ? 2 : 1) : 0);
          u16x4 pk;
          #pragma unroll
          for (int nt = 0; nt < 4; ++nt) {
            float vx = fmaf(S[mt][nt][r] * rk4[nt], rq, bb4[nt]);
            if (labi != labj[nt]) vx -= 144.2695f;
            pk[nt] = f2bf(__builtin_amdgcn_exp2f(vx));
          }
          *(u16x4*)(QB + i * 128 + swzb(i, c16 * 8)) = pk;
        }
    } else {
      #pragma unroll
      for (int mt = 0; mt < 4; ++mt)
        #pragma unroll
        for (int r = 0; r < 4; ++r) {
          int i = mt * 16 + 4 * g + r;
          float rq = nqp[i];
          f32x4 bb4 = biasv[(w * 64 + i) * 16 + c16];
          u16x4 pk;
          #pragma unroll
          for (int nt = 0; nt < 4; ++nt) {
            float vx = fmaf(S[mt][nt][r] * rk4[nt], rq, bb4[nt]);
            pk[nt] = f2bf(__builtin_amdgcn_exp2f(vx));
          }
          *(u16x4*)(QB + i * 128 + swzb(i, c16 * 8)) = pk;
        }
    }

    // PV + rowsum-via-ones: O_raw = P~ @ V ; RS = P~ @ 1 (lands in matching lanes)
    s16x8 ones;
    #pragma unroll
    for (int e = 0; e < 8; ++e) ones[e] = (short)0x3F80;
    f32x4 O[4][2], RS[4];
    #pragma unroll
    for (int a = 0; a < 4; ++a) {
      O[a][0] = f32x4{0.f,0.f,0.f,0.f};
      O[a][1] = f32x4{0.f,0.f,0.f,0.f};
      RS[a]   = f32x4{0.f,0.f,0.f,0.f};
    }
    __builtin_amdgcn_s_setprio(1);
    #pragma unroll
    for (int k0 = 0; k0 < 64; k0 += 32) {
      s16x8 pf[4];
      #pragma unroll
      for (int mt = 0; mt < 4; ++mt) {
        int row = mt * 16 + c16;
        pf[mt] = *(const s16x8*)(QB + row * 128 + swzb(row, (k0 + g * 8) * 2));
      }
      #pragma unroll
      for (int nt = 0; nt < 2; ++nt) {
        int d = nt * 16 + c16;
        s16x8 vf = *(const s16x8*)(QB + 8192 + d * 128 + swzb(d, (k0 + g * 8) * 2));
        #pragma unroll
        for (int mt = 0; mt < 4; ++mt)
          O[mt][nt] = __builtin_amdgcn_mfma_f32_16x16x32_bf16(pf[mt], vf, O[mt][nt], 0, 0, 0);
      }
      #pragma unroll
      for (int mt = 0; mt < 4; ++mt)
        RS[mt] = __builtin_amdgcn_mfma_f32_16x16x32_bf16(pf[mt], ones, RS[mt], 0, 0, 0);
    }
    __builtin_amdgcn_s_setprio(0);
    // normalize + packed O store into P rows bytes 0..63 (d' pairing; P reads done)
    #pragma unroll
    for (int mt = 0; mt < 4; ++mt)
      #pragma unroll
      for (int r = 0; r < 4; ++r) {
        float inv = __builtin_amdgcn_rcpf(fmaxf(RS[mt][r], 1e-35f));
        int i = mt * 16 + 4 * g + r;
        unsigned u = (unsigned)f2bf(O[mt][0][r] * inv) | ((unsigned)f2bf(O[mt][1][r] * inv) << 16);
        *(unsigned*)(QB + i * 128 + swzb(i, c16 * 4)) = u;
      }
  }
  __syncthreads();   // B2: all heads' O complete

  // ---------- Phase P: proj (K = 8 heads x 32, d-perm baked in projw) ----------
  // Y is in the top 32KB (disjoint from slabs), so no barrier between slab reads and Y writes.
  {
    f32x4 aP[2][4];
    #pragma unroll
    for (int a = 0; a < 2; ++a)
      #pragma unroll
      for (int b = 0; b < 4; ++b) aP[a][b] = f32x4{0.f,0.f,0.f,0.f};
    __builtin_amdgcn_s_setprio(1);
    #pragma unroll 2
    for (int k0 = 0; k0 < 256; k0 += 32) {
      int hk = k0 >> 5;
      const char* OBk = sm + L_SLAB + hk * 12288;
      s16x8 af[4];
      #pragma unroll
      for (int mt = 0; mt < 4; ++mt) {
        int row = mt * 16 + c16;
        af[mt] = *(const s16x8*)(OBk + row * 128 + swzb(row, g * 16));
      }
      #pragma unroll
      for (int t2 = 0; t2 < 2; ++t2) {
        s16x8 bfr = *(const s16x8*)(projw + (((2*w + t2) * 32 + 4*hk + g) * 16 + c16) * 8);
        #pragma unroll
        for (int mt = 0; mt < 4; ++mt)
          aP[t2][mt] = __builtin_amdgcn_mfma_f32_16x16x32_bf16(af[mt], bfr, aP[t2][mt], 0, 0, 0);
      }
    }
    __builtin_amdgcn_s_setprio(0);
    #pragma unroll
    for (int t2 = 0; t2 < 2; ++t2) {
      int col = (2*w + t2) * 16 + c16;
      float pb = proj_b[col];
      #pragma unroll
      for (int mt = 0; mt < 4; ++mt)
        #pragma unroll
        for (int r = 0; r < 4; ++r) {
          int i = mt * 16 + 4 * g + r;
          *(unsigned short*)(sm + L_Y + i * 512 + swzb(i, col * 2)) = f2bf(aP[t2][mt][r] + pb);
        }
    }
  }
  __syncthreads();   // B4 (Y complete; NQ/NK dead)

  // ---------- LN1 + residual: y = LN(o)*g+b + xw, in place on Y; 8 lanes/row ----------
  {
    int t = tid >> 3, oc = tid & 7;
    float v[32];
    float s1 = 0.f;
    #pragma unroll
    for (int b2 = 0; b2 < 4; ++b2) {
      s16x8 vb = *(const s16x8*)(sm + L_Y + t * 512 + swzb(t, oc * 64 + b2 * 16));
      #pragma unroll
      for (int e = 0; e < 8; ++e) { float fv = bf2f((unsigned short)vb[e]); v[b2*8+e] = fv; s1 += fv; }
    }
    s1 += __shfl_xor(s1, 1);
    s1 += __shfl_xor(s1, 2);
    s1 += __shfl_xor(s1, 4);
    float mu = s1 * (1.f / 256.f);
    float s2 = 0.f;
    #pragma unroll
    for (int e = 0; e < 32; ++e) { float d = v[e] - mu; s2 += d * d; }
    s2 += __shfl_xor(s2, 1);
    s2 += __shfl_xor(s2, 2);
    s2 += __shfl_xor(s2, 4);
    float rs = __builtin_amdgcn_rsqf(s2 * (1.f / 256.f) + 1e-5f);
    #pragma unroll
    for (int b2 = 0; b2 < 4; ++b2) {
      s16x8 xb = *(const s16x8*)(sm + L_XW + t * 512 + swzb(t, oc * 64 + b2 * 16));
      s16x8 yb;
      #pragma unroll
      for (int e = 0; e < 8; ++e) {
        int c = oc * 32 + b2 * 8 + e;
        float yv = (v[b2*8+e] - mu) * rs * ln1w[c] + ln1b[c] + bf2f((unsigned short)xb[e]);
        yb[e] = (short)f2bf(yv);
      }
      *(s16x8*)(sm + L_Y + t * 512 + swzb(t, oc * 64 + b2 * 16)) = yb;
    }
  }
  __syncthreads();   // B5: Y final; XW/slabs dead -> H buffers

  // ---------- MLP fc1: cc-paired K-sweeps, barrier-free; sigmoid-form gelu ----------
  {
    const int Hoff[4] = {L_H0, L_H1, L_H2, L_H3};
    #pragma unroll 1
    for (int cp = 0; cp < 2; ++cp) {
      f32x4 acc1[2][2][4];
      #pragma unroll
      for (int a = 0; a < 2; ++a)
        #pragma unroll
        for (int b = 0; b < 2; ++b)
          #pragma unroll
          for (int m = 0; m < 4; ++m) acc1[a][b][m] = f32x4{0.f,0.f,0.f,0.f};
      __builtin_amdgcn_s_setprio(1);
      for (int k0 = 0; k0 < 256; k0 += 32) {
        s16x8 af[4];
        #pragma unroll
        for (int mt = 0; mt < 4; ++mt) {
          int row = mt * 16 + c16;
          af[mt] = *(const s16x8*)(sm + L_Y + row * 512 + swzb(row, (k0 + g * 8) * 2));
        }
        #pragma unroll
        for (int cc2 = 0; cc2 < 2; ++cc2) {
          int cc = cp * 2 + cc2;
          #pragma unroll
          for (int t2 = 0; t2 < 2; ++t2) {
            int gt = cc * 16 + 2*w + t2;
            s16x8 bfr = *(const s16x8*)(fc1w + ((gt * 32 + (k0 >> 3) + g) * 16 + c16) * 8);
            #pragma unroll
            for (int mt = 0; mt < 4; ++mt)
              acc1[cc2][t2][mt] = __builtin_amdgcn_mfma_f32_16x16x32_bf16(af[mt], bfr, acc1[cc2][t2][mt], 0, 0, 0);
          }
        }
      }
      __builtin_amdgcn_s_setprio(0);
      #pragma unroll
      for (int cc2 = 0; cc2 < 2; ++cc2) {
        int cc = cp * 2 + cc2;
        char* HB = sm + Hoff[cc];
        float b1v0 = fc1b[cc * 256 + 32 * w + c16];
        float b1v1 = fc1b[cc * 256 + 32 * w + 16 + c16];
        #pragma unroll
        for (int mt = 0; mt < 4; ++mt)
          #pragma unroll
          for (int r = 0; r < 4; ++r) {
            int i = mt * 16 + 4 * g + r;
            float u0 = acc1[cc2][0][mt][r] + b1v0;
            float u1 = acc1[cc2][1][mt][r] + b1v1;
            // gelu ~ u * sigmoid(1.702u) = u * rcp(1 + 2^(-2.45538u)); clamp-free
            float e0 = __builtin_amdgcn_exp2f(-2.45538f * u0);
            float e1 = __builtin_amdgcn_exp2f(-2.45538f * u1);
            float g0 = u0 * __builtin_amdgcn_rcpf(1.f + e0);
            float g1 = u1 * __builtin_amdgcn_rcpf(1.f + e1);
            unsigned u = (unsigned)f2bf(g0) | ((unsigned)f2bf(g1) << 16);
            *(unsigned*)(HB + i * 512 + swzb(i, w * 64 + c16 * 4)) = u;
          }
      }
    }
  }
  __syncthreads();   // B6: all H complete

  // ---------- MLP fc2: barrier-free pass over K=1024 (perm baked in fc2w) ----------
  f32x4 acc2[2][4];
  #pragma unroll
  for (int a = 0; a < 2; ++a)
    #pragma unroll
    for (int b = 0; b < 4; ++b) acc2[a][b] = f32x4{0.f,0.f,0.f,0.f};
  {
    const int Hoff[4] = {L_H0, L_H1, L_H2, L_H3};
    __builtin_amdgcn_s_setprio(1);
    #pragma unroll 1
    for (int cc = 0; cc < 4; ++cc) {
      const char* HB = sm + Hoff[cc];
      for (int k0 = 0; k0 < 256; k0 += 32) {
        s16x8 af[4];
        #pragma unroll
        for (int mt = 0; mt < 4; ++mt) {
          int row = mt * 16 + c16;
          af[mt] = *(const s16x8*)(HB + row * 512 + swzb(row, (k0 + g * 8) * 2));
        }
        #pragma unroll
        for (int t2 = 0; t2 < 2; ++t2) {
          int kg = cc * 32 + (k0 >> 3) + g;
          s16x8 bfr = *(const s16x8*)(fc2w + (((2*w + t2) * 128 + kg) * 16 + c16) * 8);
          #pragma unroll
          for (int mt = 0; mt < 4; ++mt)
            acc2[t2][mt] = __builtin_amdgcn_mfma_f32_16x16x32_bf16(af[mt], bfr, acc2[t2][mt], 0, 0, 0);
        }
      }
    }
    __builtin_amdgcn_s_setprio(0);
  }
  __syncthreads();   // B7: fc2 H reads done (MB overwrites H0)

  // ---------- fc2 epilogue -> MB ----------
  #pragma unroll
  for (int t2 = 0; t2 < 2; ++t2) {
    int col = (2*w + t2) * 16 + c16;
    float b2v = fc2b[col];
    #pragma unroll
    for (int mt = 0; mt < 4; ++mt)
      #pragma unroll
      for (int r = 0; r < 4; ++r) {
        int i = mt * 16 + 4 * g + r;
        *(unsigned short*)(sm + L_MB + i * 512 + swzb(i, col * 2)) = f2bf(acc2[t2][mt][r] + b2v);
      }
  }
  __syncthreads();   // B8

  // ---------- LN2 + residual; direct bf16 store to sout ----------
  {
    int t2 = tid >> 3, oc = tid & 7;
    float v[32];
    float s1 = 0.f;
    #pragma unroll
    for (int b2 = 0; b2 < 4; ++b2) {
      s16x8 vb = *(const s16x8*)(sm + L_MB + t2 * 512 + swzb(t2, oc * 64 + b2 * 16));
      #pragma unroll
      for (int e = 0; e < 8; ++e) { float fv = bf2f((unsigned short)vb[e]); v[b2*8+e] = fv; s1 += fv; }
    }
    s1 += __shfl_xor(s1, 1);
    s1 += __shfl_xor(s1, 2);
    s1 += __shfl_xor(s1, 4);
    float mu = s1 * (1.f / 256.f);
    float s2 = 0.f;
    #pragma unroll
    for (int e = 0; e < 32; ++e) { float d = v[e] - mu; s2 += d * d; }
    s2 += __shfl_xor(s2, 1);
    s2 += __shfl_xor(s2, 2);
    s2 += __shfl_xor(s2, 4);
    float rs = __builtin_amdgcn_rsqf(s2 * (1.f / 256.f) + 1e-5f);
    int rp = (wi * 8 + (t2 >> 3) + 4) & 255;
    int cp = (wj * 8 + (t2 & 7) + 4) & 255;
    size_t pix = (size_t)bb * 65536 + rp * 256 + cp;
    unsigned short* so = sout + pix * 256 + oc * 32;
    #pragma unroll
    for (int b2 = 0; b2 < 4; ++b2) {
      s16x8 yb = *(const s16x8*)(sm + L_Y + t2 * 512 + swzb(t2, oc * 64 + b2 * 16));
      s16x8 pk;
      #pragma unroll
      for (int e = 0; e < 8; ++e) {
        int c = oc * 32 + b2 * 8 + e;
        float yv = (v[b2*8+e] - mu) * rs * ln2w[c] + ln2b[c] + bf2f((unsigned short)yb[e]);
        pk[e] = (short)f2bf(yv);
      }
      *(s16x8*)(so + b2 * 8) = pk;
    }
  }
}

extern "C" void kernel_launch(void* const* d_in, const int* in_sizes, int n_in,
                              void* d_out, int out_size, void* d_ws, size_t ws_size,
                              hipStream_t stream) {
  const float* x      = (const float*)d_in[0];
  const float* qkv_w  = (const float*)d_in[1];
  const float* ls     = (const float*)d_in[2];
  const float* proj_w = (const float*)d_in[3];
  const float* proj_b = (const float*)d_in[4];
  const float* ln1w   = (const float*)d_in[5];
  const float* ln1b   = (const float*)d_in[6];
  const float* fc1_w  = (const float*)d_in[7];
  const float* fc1b   = (const float*)d_in[8];
  const float* fc2_w  = (const float*)d_in[9];
  const float* fc2b   = (const float*)d_in[10];
  const float* ln2w   = (const float*)d_in[11];
  const float* ln2b   = (const float*)d_in[12];
  const float* cpb_w1 = (const float*)d_in[13];
  const float* cpb_b1 = (const float*)d_in[14];
  const float* cpb_w2 = (const float*)d_in[15];
  unsigned char* wsb = (unsigned char*)d_ws;
  float* out = (float*)d_out;

  hipFuncSetAttribute(reinterpret_cast<const void*>(swin_block_kernel),
                      hipFuncAttributeMaxDynamicSharedMemorySize, SMEM_BYTES);

  prep_kernel<<<11265, 256, 0, stream>>>(qkv_w, proj_w, fc1_w, fc2_w,
                                         cpb_w1, cpb_b1, cpb_w2, x, ls, wsb);
  swin_block_kernel<<<2048, 512, SMEM_BYTES, stream>>>(
      ls, proj_b, ln1w, ln1b, fc1b, fc2b, ln2w, ln2b, wsb);
  transpose_out_kernel<<<8192, 256, 0, stream>>>(wsb, out);
}